// Round 9
// baseline (434.522 us; speedup 1.0000x reference)
//
#include <hip/hip_runtime.h>
#include <stdint.h>

#define BATCH_N   131072
#define HID       256
#define SPIKE_DIM 128
#define COORD_DIM 64
#define IN_DIM    192
#define STEPS     25

typedef float f4  __attribute__((ext_vector_type(4)));
typedef short bf8 __attribute__((ext_vector_type(8)));
typedef unsigned short us4 __attribute__((ext_vector_type(4)));

// ws layout (floats):
//   W0b  [256][192] bf16   at 0            (24576 floats, legacy row-major)
//   W1T  [256][256] fp32   at 24576
//   WoT  [256][64]  fp32   at 90112
//   scalars               at 106496: [0]=max(b1,0), [1]=max(W1+,0)
//   W0F  pre-tiled MFMA B-frags [n=16][kc=6][lane=64] x 16B at 106512 (96KB)
#define W1T_OFF  24576
#define WOT_OFF  90112
#define SCAL_OFF 106496
#define W0F_OFF  106512

static __device__ __forceinline__ unsigned short f2bf(float f) {
  union { float f; unsigned u; } v; v.f = f;
  unsigned r = v.u + 0x7FFF + ((v.u >> 16) & 1);   // RNE
  return (unsigned short)(r >> 16);
}

__global__ __launch_bounds__(256)
void prep_kernel(const float* __restrict__ W0,
                 const float* __restrict__ W1,
                 const float* __restrict__ Wout,
                 const float* __restrict__ b1,
                 float* __restrict__ ws) {
  const int t = threadIdx.x, b = blockIdx.x;
  if (b > 512) {
    // pre-tiled W0 fragments: frag(n,kc,lane) = W0[n*16+(lane&15)]
    //   [kc*32+(lane>>4)*8 .. +8] as 8 bf16 (16B). snn stages this to LDS
    //   and reads it back 1KB-contiguous per (n,kc) -> conflict-free.
    int fi = (b - 513) * 256 + t;            // 0..6143
    int lane = fi & 63, kcn = fi >> 6;
    int kc = kcn % 6, n = kcn / 6;
    const float* s = W0 + (size_t)(n*16 + (lane & 15))*IN_DIM
                        + kc*32 + (lane >> 4)*8;
    uint4 o;
    o.x = (unsigned)f2bf(s[0]) | ((unsigned)f2bf(s[1]) << 16);
    o.y = (unsigned)f2bf(s[2]) | ((unsigned)f2bf(s[3]) << 16);
    o.z = (unsigned)f2bf(s[4]) | ((unsigned)f2bf(s[5]) << 16);
    o.w = (unsigned)f2bf(s[6]) | ((unsigned)f2bf(s[7]) << 16);
    ((uint4*)(ws + W0F_OFF))[fi] = o;
    return;
  }
  if (b == 512) {
    // screen scalar b1max0 via wave-reduce + atomicMax on float bits
    // (>=0 values: uint order == float order; ws[SCAL..] pre-zeroed)
    unsigned u = __float_as_uint(fmaxf(b1[t], 0.f));
    #pragma unroll
    for (int o = 1; o < 64; o <<= 1) {
      unsigned v = __shfl_xor(u, o);
      u = v > u ? v : u;
    }
    if ((t & 63) == 0) atomicMax((unsigned*)(ws + SCAL_OFF), u);
    return;
  }
  int idx = b * 256 + t;
  if (idx < HID*IN_DIM) {               // W0b elementwise (legacy)
    ((unsigned short*)ws)[idx] = f2bf(W0[idx]);
  }
  int i1 = idx - HID*IN_DIM;            // W1T[j][i] = W1[i][j]
  if (i1 >= 0 && i1 < HID*HID) {
    int j = i1 >> 8, i = i1 & 255;
    ws[W1T_OFF + i1] = W1[i*HID + j];
  }
  int i2 = idx - (HID*IN_DIM + HID*HID);// WoT[k][c] = Wout[128+c][k]
  if (i2 >= 0 && i2 < HID*COORD_DIM) {
    int k = i2 >> 6, c = i2 & 63;
    ws[WOT_OFF + i2] = Wout[(SPIKE_DIM + c)*HID + k];
  }
  if (b < 64) {                         // W1 max: 64 blocks cover 16384 f4
    f4 v = ((const f4*)W1)[idx];
    float m = fmaxf(fmaxf(v.x, v.y), fmaxf(v.z, v.w));
    m = fmaxf(m, 0.f);
    unsigned u = __float_as_uint(m);
    #pragma unroll
    for (int o = 1; o < 64; o <<= 1) {
      unsigned w = __shfl_xor(u, o);
      u = w > u ? w : u;
    }
    if ((t & 63) == 0) atomicMax((unsigned*)(ws + SCAL_OFF + 1), u);
  }
}

// Contiguous chunk load: a wave's 16 elements are 8KB (spk) + 4KB (crd)
// CONTIGUOUS. 12 f4/lane, plain loads (keep inputs L3-resident; R5 lesson:
// never scattered-NT). Issued one chunk ahead of use.
#define XLOAD(dst, ce_)                                                \
  { const f4* sp4_ = (const f4*)spk + (size_t)(ce_)*32;                \
    const f4* cr4_ = (const f4*)crd + (size_t)(ce_)*16;                \
    _Pragma("unroll")                                                  \
    for (int j = 0; j < 8; ++j) dst[j]   = sp4_[j*64 + lane];          \
    _Pragma("unroll")                                                  \
    for (int j = 0; j < 4; ++j) dst[8+j] = cr4_[j*64 + lane];          \
  }

#define CVT(h, r) { h.x = f2bf(r.x); h.y = f2bf(r.y); h.z = f2bf(r.z); h.w = f2bf(r.w); }

__global__ __launch_bounds__(512, 2)
void snn_kernel(const float* __restrict__ spk,
                const float* __restrict__ crd,
                const float* __restrict__ W0,
                const float* __restrict__ b0,
                const float* __restrict__ b1,
                const float* __restrict__ bout,
                const float* __restrict__ ws,
                float* __restrict__ out) {
  // R9: barrier-free autonomous waves (R5 structure, defects fixed).
  //   * ONE barrier (after W0F block-stage). After it, waves free-run:
  //     within-wave counts (quad shfl + ballot), per-wave LDS x-slice
  //     (in-wave lgkmcnt ordering, no syncthreads), stores stream
  //     continuously -> write duty cycle ~100% (the R3/R6 1.45 TB/s was
  //     barrier-burst duty, not drain rate).
  //   * x loads contiguous+plain; W0 frags pre-tiled by prep (no in-kernel
  //     scatter, conflict-free 1KB b128 LDS reads).
  __shared__ uint4 w0f4[6144];                       // 96 KB B-fragments
  __shared__ unsigned short xsl[8][16*200];          // 51.2 KB per-wave slices

  const int tid  = threadIdx.x;
  const int lane = tid & 63;
  const int wv   = tid >> 6;            // wave 0..7
  const int quad = lane >> 4;
  const int l15  = lane & 15;
  const int i4   = lane * 4;
  const int gw   = blockIdx.x * 8 + wv; // global wave 0..2047; 4 chunks each

  // chunk 0 loads in flight first
  f4 stg[12];
  XLOAD(stg, gw*64)

  // W0F global->LDS, coalesced flat copy (overlaps the above)
  {
    const uint4* src = (const uint4*)(ws + W0F_OFF);
    #pragma unroll
    for (int i = 0; i < 12; ++i) w0f4[tid + i*512] = src[tid + i*512];
  }

  // per-lane constants
  float b0n[16];
  #pragma unroll
  for (int n = 0; n < 16; ++n) b0n[n] = b0[n*16 + l15];
  const float b1mx = ws[SCAL_OFF];
  const float w1pm = ws[SCAL_OFF + 1];
  const float bc = bout[SPIKE_DIM + lane];
  const f4 bc4 = *(const f4*)&bout[SPIKE_DIM + (lane & 15)*4];

  __syncthreads();                      // the ONLY barrier
  unsigned short* myxs = xsl[wv];
  const unsigned short* w0s = (const unsigned short*)w0f4;

  for (int m = 0; m < 4; ++m) {
    const int ce0 = (gw*4 + m) * 16;

    // publish staged x to own slice (in-wave DS ordering; no barrier).
    // spk: instr j covers elements 2j+(lane>>5), cols (lane&31)*4.
    #pragma unroll
    for (int j = 0; j < 8; ++j) {
      us4 h; CVT(h, stg[j])
      *(us4*)&myxs[(2*j + (lane >> 5))*200 + (lane & 31)*4] = h;
    }
    #pragma unroll
    for (int j = 0; j < 4; ++j) {
      us4 h; CVT(h, stg[8+j])
      *(us4*)&myxs[(4*j + (lane >> 4))*200 + SPIKE_DIM + (lane & 15)*4] = h;
    }
    if (m < 3) XLOAD(stg, ce0 + 16)     // issue-early: hides under n-loop

    // A fragments (compiler inserts lgkmcnt after the ds_writes above)
    bf8 afr[6];
    #pragma unroll
    for (int kc = 0; kc < 6; ++kc)
      afr[kc] = *(const bf8*)&myxs[l15*200 + kc*32 + quad*8];

    // ---- 16 n-tiles x (6 LDS B-frags + 6 MFMA); counts in-register ----
    // C/D layout: col(neuron)=l15, row(element)=quad*4+reg.
    // Rigor: exact-spiking layer-0 neuron has exact c0 >= 0.96; bf16-input
    // MFMA error <= ~0.05 (f32 accumulate) -> acc+b0 >= 0.90 counts it
    // (strict superset). 16-bit packed fields: max 256 can't wrap.
    unsigned c01 = 0, c23 = 0;
    #pragma unroll
    for (int n = 0; n < 16; ++n) {
      f4 acc; acc.x = acc.y = acc.z = acc.w = 0.f;
      #pragma unroll
      for (int kc = 0; kc < 6; ++kc) {
        bf8 b = *(const bf8*)&w0s[(size_t)((n*6 + kc)*64 + lane)*8];
        acc = __builtin_amdgcn_mfma_f32_16x16x32_bf16(afr[kc], b, acc, 0, 0, 0);
      }
      const float bn = b0n[n];
      c01 += (acc.x + bn >= 0.90f) ? 1u       : 0u;
      c01 += (acc.y + bn >= 0.90f) ? 0x10000u : 0u;
      c23 += (acc.z + bn >= 0.90f) ? 1u       : 0u;
      c23 += (acc.w + bn >= 0.90f) ? 0x10000u : 0u;
    }
    // quad-local reduce over the 16 neuron-columns
    c01 += __shfl_xor(c01, 1, 16); c23 += __shfl_xor(c23, 1, 16);
    c01 += __shfl_xor(c01, 2, 16); c23 += __shfl_xor(c23, 2, 16);
    c01 += __shfl_xor(c01, 4, 16); c23 += __shfl_xor(c23, 4, 16);
    c01 += __shfl_xor(c01, 8, 16); c23 += __shfl_xor(c23, 8, 16);

    // lane j<16 fetches element j's total; one ballot -> wave-uniform mask
    unsigned a01 = __shfl(c01, (lane & 12) << 2);
    unsigned a23 = __shfl(c23, (lane & 12) << 2);
    unsigned cw  = (lane & 2) ? a23 : a01;
    unsigned nspk = (cw >> ((lane & 1) << 4)) & 0xFFFFu;
    // Screen: c1_i(t) <= max(b1,0) + nspk*max(W1+,0) < 0.97 => s1 == 0 =>
    // outputs (0, b_out) EXACT. Garbage scalars fail closed (exact path).
    bool fast = (lane < 16) && (b1mx + w1pm * (float)nspk < 0.97f);
    unsigned mask16 = (unsigned)__ballot(fast) & 0xFFFFu;

    // ---- streaming NT stores (no barrier follows -> no vmcnt(0) stall)
    #pragma unroll
    for (int ee = 0; ee < 16; ++ee) {
      if (mask16 & (1u << ee)) {
        f4 z; z.x = z.y = z.z = z.w = 0.f;
        __builtin_nontemporal_store(z,
            (f4*)&out[(size_t)(ce0 + ee)*HID + i4]);
      }
    }
    #pragma unroll
    for (int g = 0; g < 4; ++g) {       // coords: f4-batched when group uniform
      unsigned gm = (mask16 >> (g*4)) & 15u;
      if (gm == 15u) {
        const size_t e = (size_t)ce0 + g*4 + (lane >> 4);
        __builtin_nontemporal_store(bc4,
            (f4*)&out[(size_t)BATCH_N*HID + e*COORD_DIM + (lane & 15)*4]);
      } else {
        #pragma unroll
        for (int q = 0; q < 4; ++q) {
          if (gm & (1u << q)) {
            const size_t e = (size_t)ce0 + g*4 + q;
            __builtin_nontemporal_store(bc,
                &out[(size_t)BATCH_N*HID + e*COORD_DIM + lane]);
          }
        }
      }
    }

    // rare (~1e-4/element): verbatim exact path overwrites
    if (__builtin_expect(mask16 != 0xFFFFu, 0)) {
      const float* W1T = ws + W1T_OFF;
      const float* WoT = ws + WOT_OFF;
      f4 b0v = *(const f4*)&b0[i4];
      f4 b1v = *(const f4*)&b1[i4];
      for (int ee = 0; ee < 16; ++ee) {
        if (mask16 & (1u << ee)) continue;
        const size_t e = (size_t)ce0 + ee;

        // ---- exact c0 recompute from global x, W0 (serial FMA, j ascending)
        float cx = 0.f, cy = 0.f, cz = 0.f, cw_ = 0.f;
        const float* q0 = W0 + (size_t)(i4+0)*IN_DIM;
        const float* q1 = W0 + (size_t)(i4+1)*IN_DIM;
        const float* q2 = W0 + (size_t)(i4+2)*IN_DIM;
        const float* q3 = W0 + (size_t)(i4+3)*IN_DIM;
        const float* xs_ = spk + e*SPIKE_DIM;
        const float* xc_ = crd + e*COORD_DIM;
        for (int j = 0; j < SPIKE_DIM; ++j) {
          float xj = xs_[j];
          cx = fmaf(xj, q0[j], cx); cy = fmaf(xj, q1[j], cy);
          cz = fmaf(xj, q2[j], cz); cw_ = fmaf(xj, q3[j], cw_);
        }
        for (int j = 0; j < COORD_DIM; ++j) {
          float xj = xc_[j];
          cx = fmaf(xj, q0[SPIKE_DIM+j], cx); cy = fmaf(xj, q1[SPIKE_DIM+j], cy);
          cz = fmaf(xj, q2[SPIKE_DIM+j], cz); cw_ = fmaf(xj, q3[SPIKE_DIM+j], cw_);
        }
        const float c0x = cx + b0v.x, c0y = cy + b0v.y;
        const float c0z = cz + b0v.z, c0w = cw_ + b0v.w;

        // ---- honest 25-step simulation (exact)
        float v0x=0.f, v0y=0.f, v0z=0.f, v0w=0.f;
        float v1x=0.f, v1y=0.f, v1z=0.f, v1w=0.f;
        float s1x=0.f, s1y=0.f, s1z=0.f, s1w=0.f;
        unsigned long long mm;

        for (int t = 0; t < STEPS; ++t) {
          bool sp;
          unsigned long long m0, m1, m2, m3;
          v0x = __fmul_rn(0.7f, v0x) + __fmul_rn(0.3f, c0x);
          sp = (v0x >= 1.0f); m0 = __ballot(sp); if (sp) v0x = 0.f;
          v0y = __fmul_rn(0.7f, v0y) + __fmul_rn(0.3f, c0y);
          sp = (v0y >= 1.0f); m1 = __ballot(sp); if (sp) v0y = 0.f;
          v0z = __fmul_rn(0.7f, v0z) + __fmul_rn(0.3f, c0z);
          sp = (v0z >= 1.0f); m2 = __ballot(sp); if (sp) v0z = 0.f;
          v0w = __fmul_rn(0.7f, v0w) + __fmul_rn(0.3f, c0w);
          sp = (v0w >= 1.0f); m3 = __ballot(sp); if (sp) v0w = 0.f;

          float c1x = b1v.x, c1y = b1v.y, c1z = b1v.z, c1w = b1v.w;
          f4 wcur; wcur.x = wcur.y = wcur.z = wcur.w = 0.f;
          int have = 0;
          #define PROCQ(MASK, Q)                                                  \
            mm = (MASK);                                                          \
            while (mm) {                                                          \
              int l = __builtin_ctzll(mm); mm &= mm - 1;                          \
              f4 wn = *(const f4*)&W1T[(l*4 + (Q))*HID + i4];                     \
              if (have) { c1x += wcur.x; c1y += wcur.y; c1z += wcur.z; c1w += wcur.w; } \
              wcur = wn; have = 1;                                                \
            }
          PROCQ(m0, 0)
          PROCQ(m1, 1)
          PROCQ(m2, 2)
          PROCQ(m3, 3)
          #undef PROCQ
          if (have) { c1x += wcur.x; c1y += wcur.y; c1z += wcur.z; c1w += wcur.w; }

          v1x = __fmul_rn(0.7f, v1x) + __fmul_rn(0.3f, c1x);
          sp = (v1x >= 1.0f); s1x = sp ? 1.f : 0.f; if (sp) v1x = 0.f;
          v1y = __fmul_rn(0.7f, v1y) + __fmul_rn(0.3f, c1y);
          sp = (v1y >= 1.0f); s1y = sp ? 1.f : 0.f; if (sp) v1y = 0.f;
          v1z = __fmul_rn(0.7f, v1z) + __fmul_rn(0.3f, c1z);
          sp = (v1z >= 1.0f); s1z = sp ? 1.f : 0.f; if (sp) v1z = 0.f;
          v1w = __fmul_rn(0.7f, v1w) + __fmul_rn(0.3f, c1w);
          sp = (v1w >= 1.0f); s1w = sp ? 1.f : 0.f; if (sp) v1w = 0.f;
        }

        f4 res; res.x = s1x; res.y = s1y; res.z = s1z; res.w = s1w;
        __builtin_nontemporal_store(res, (f4*)&out[e*HID + i4]);

        unsigned long long f0 = __ballot(s1x > 0.5f);
        unsigned long long f1 = __ballot(s1y > 0.5f);
        unsigned long long f2 = __ballot(s1z > 0.5f);
        unsigned long long f3 = __ballot(s1w > 0.5f);
        float cacc = bc;
        #define CPROCQ(MASK, Q)                                 \
          mm = (MASK);                                          \
          while (mm) {                                          \
            int l = __builtin_ctzll(mm); mm &= mm - 1;          \
            cacc += WoT[(l*4 + (Q))*COORD_DIM + lane];          \
          }
        CPROCQ(f0, 0)
        CPROCQ(f1, 1)
        CPROCQ(f2, 2)
        CPROCQ(f3, 3)
        #undef CPROCQ
        __builtin_nontemporal_store(cacc,
            &out[(size_t)BATCH_N*HID + e*COORD_DIM + lane]);
      }
    }
  }
}

extern "C" void kernel_launch(void* const* d_in, const int* in_sizes, int n_in,
                              void* d_out, int out_size, void* d_ws, size_t ws_size,
                              hipStream_t stream) {
  (void)in_sizes; (void)n_in; (void)out_size; (void)ws_size;
  const float* spk = (const float*)d_in[0];
  const float* crd = (const float*)d_in[1];
  const float* W0  = (const float*)d_in[2];
  const float* b0  = (const float*)d_in[3];
  const float* W1  = (const float*)d_in[4];
  const float* b1  = (const float*)d_in[5];
  const float* Wo  = (const float*)d_in[6];
  const float* bo  = (const float*)d_in[7];
  float* ws  = (float*)d_ws;
  float* out = (float*)d_out;

  hipMemsetAsync(ws + SCAL_OFF, 0, 8, stream);   // seed for atomicMax
  hipLaunchKernelGGL(prep_kernel, dim3(537), dim3(256), 0, stream, W0, W1, Wo, b1, ws);
  hipLaunchKernelGGL(snn_kernel, dim3(256), dim3(512), 0, stream,
                     spk, crd, W0, b0, b1, bo, ws, out);
}